// Round 2
// baseline (64.626 us; speedup 1.0000x reference)
//
#include <hip/hip_runtime.h>

// Problem constants (from reference): x[64][32768][15] f32, hidden sizes 4/4/4.
#define SEQ   64
#define BATCH 32768
#define FEAT  15
#define SLAB  (BATCH * FEAT)   // dwords per timestep slab of x

__device__ __forceinline__ float fast_rcp(float x) { return __builtin_amdgcn_rcpf(x); }

__device__ __forceinline__ float fast_sigmoid(float x) {
    // 1 / (1 + e^-x); stable at both extremes (rcp(inf)=0).
    return fast_rcp(1.0f + __expf(-x));
}
__device__ __forceinline__ float fast_tanh(float x) {
    // 1 - 2/(1 + e^{2x}); stable at both extremes.
    return 1.0f - 2.0f * fast_rcp(1.0f + __expf(2.0f * x));
}

// Quad (4-lane) DPP move: CTRL = j*0x55 broadcasts lane j of each quad.
template <int CTRL>
__device__ __forceinline__ float qmov(float v) {
    return __int_as_float(
        __builtin_amdgcn_mov_dpp(__float_as_int(v), CTRL, 0xf, 0xf, false));
}

__global__ __launch_bounds__(256) void lstm_fused(
    const float* __restrict__ x,
    const float* __restrict__ w1,  const float* __restrict__ b1,
    const float* __restrict__ w2,  const float* __restrict__ b2,
    const float* __restrict__ wih, const float* __restrict__ whh,
    const float* __restrict__ bih, const float* __restrict__ bhh,
    const float* __restrict__ w3,  const float* __restrict__ b3,
    float* __restrict__ out)
{
    // 4 waves/block; each wave owns 16 batch elements; 4 lanes per element.
    // 64 float4 per buffer: slots 60..63 are pad so lanes 60-63 need no predication.
    __shared__ float4 lds4[4][2][64];   // 8 KiB/block

    const int tid = threadIdx.x;
    const int w   = tid >> 6;          // wave in block
    const int l   = tid & 63;          // lane
    const int u   = l & 3;             // hidden-unit index this lane owns
    const int e   = l >> 2;            // element within the wave's 16
    const int ewave = blockIdx.x * 64 + w * 16;  // global element base for wave
    const int ll  = (l < 60) ? l : 59; // clamp: lanes 60-63 duplicate lane 59's load (in-bounds)

    // ---- per-lane weights (lane handles hidden unit u of every layer) ----
    float W1[FEAT], W2[4], WI[16], WH[16], BI[4];
#pragma unroll
    for (int f = 0; f < FEAT; ++f) W1[f] = w1[u * FEAT + f];
    const float B1v = b1[u];
#pragma unroll
    for (int j = 0; j < 4; ++j) W2[j] = w2[u * 4 + j];
    const float B2v = b2[u];
#pragma unroll
    for (int g = 0; g < 4; ++g) {
#pragma unroll
        for (int j = 0; j < 4; ++j) {
            WI[g * 4 + j] = wih[(g * 4 + u) * 4 + j];   // torch gate order i,f,g,o
            WH[g * 4 + j] = whh[(g * 4 + u) * 4 + j];
        }
        BI[g] = bih[g * 4 + u] + bhh[g * 4 + u];
    }
    const float W3v = w3[u];
    const float B3v = b3[0];

    float*  L0 = (float*)&lds4[w][0][0];
    float*  L1 = (float*)&lds4[w][1][0];
    float4* S0 = &lds4[w][0][0];
    float4* S1 = &lds4[w][1][0];

    // wave's global source: 60 lanes x float4 = one 960 B slab-row per step
    const float4* g = (const float4*)x + (((size_t)ewave * FEAT) >> 2) + ll;
    const size_t gstep = SLAB / 4;     // float4s per timestep slab

    // ---- prologue: depth-8 prefetch (slabs 0..7), stage slab 0 ----
    float4 R[8];
#pragma unroll
    for (int j = 0; j < 8; ++j) R[j] = g[(size_t)j * gstep];
    S0[l] = R[0];

    float h = 0.0f, c = 0.0f;

    auto compute = [&](const float* L) {
        float xv[FEAT];
#pragma unroll
        for (int f = 0; f < FEAT; ++f) xv[f] = L[e * FEAT + f];
        // fc1 (unit u), 3-way split accumulation to shorten the dependent chain
        float a0 = B1v, a1 = 0.0f, a2 = 0.0f;
#pragma unroll
        for (int f = 0; f < 5; ++f) a0 = fmaf(W1[f],      xv[f],      a0);
#pragma unroll
        for (int f = 0; f < 5; ++f) a1 = fmaf(W1[5 + f],  xv[5 + f],  a1);
#pragma unroll
        for (int f = 0; f < 5; ++f) a2 = fmaf(W1[10 + f], xv[10 + f], a2);
        const float h1 = fmaxf(a0 + (a1 + a2), 0.0f);
        // fc2 (needs all 4 h1) + sigmoid
        float q0 = qmov<0x00>(h1), q1 = qmov<0x55>(h1), q2 = qmov<0xAA>(h1), q3 = qmov<0xFF>(h1);
        const float a2f = B2v + W2[0] * q0 + W2[1] * q1 + W2[2] * q2 + W2[3] * q3;
        const float h2 = fast_sigmoid(a2f);
        // input-to-gate projection (needs all 4 h2)
        q0 = qmov<0x00>(h2); q1 = qmov<0x55>(h2); q2 = qmov<0xAA>(h2); q3 = qmov<0xFF>(h2);
        float gi = BI[0] + WI[0]  * q0 + WI[1]  * q1 + WI[2]  * q2 + WI[3]  * q3;
        float gf = BI[1] + WI[4]  * q0 + WI[5]  * q1 + WI[6]  * q2 + WI[7]  * q3;
        float gg = BI[2] + WI[8]  * q0 + WI[9]  * q1 + WI[10] * q2 + WI[11] * q3;
        float go = BI[3] + WI[12] * q0 + WI[13] * q1 + WI[14] * q2 + WI[15] * q3;
        // recurrent projection (needs all 4 h_prev)
        q0 = qmov<0x00>(h); q1 = qmov<0x55>(h); q2 = qmov<0xAA>(h); q3 = qmov<0xFF>(h);
        gi += WH[0]  * q0 + WH[1]  * q1 + WH[2]  * q2 + WH[3]  * q3;
        gf += WH[4]  * q0 + WH[5]  * q1 + WH[6]  * q2 + WH[7]  * q3;
        gg += WH[8]  * q0 + WH[9]  * q1 + WH[10] * q2 + WH[11] * q3;
        go += WH[12] * q0 + WH[13] * q1 + WH[14] * q2 + WH[15] * q3;
        const float ig = fast_sigmoid(gi);
        const float fg = fast_sigmoid(gf);
        const float gt = fast_tanh(gg);
        const float og = fast_sigmoid(go);
        c = fmaf(fg, c, ig * gt);
        h = og * fast_tanh(c);
    };

    // ---- main loop: 7 iters x 8 steps, depth-8 rotating prefetch ----
    // At sub-step j of iter i (step s = 8i + j):
    //   1. issue load slab s+8 into R[j]     (its old slab-s data was staged last sub-step)
    //   2. compute step s from LDS[(s)%2]
    //   3. stage slab s+1 from R[(j+1)&7]    (that load was issued 7 sub-steps ago, ~2000 cyc)
#pragma unroll 1
    for (int i = 0; i < 7; ++i) {
        const float4* gpre = g + (size_t)(8 * i + 8) * gstep;
#pragma unroll
        for (int j = 0; j < 8; ++j) {
            R[j] = gpre[(size_t)j * gstep];
            compute((j & 1) ? L1 : L0);
            ((j & 1) ? S0 : S1)[l] = R[(j + 1) & 7];
        }
    }
    // ---- epilogue: steps 56..63, R[1..7] hold slabs 57..63 ----
#pragma unroll
    for (int j = 0; j < 8; ++j) {
        compute((j & 1) ? L1 : L0);
        if (j < 7) ((j & 1) ? S0 : S1)[l] = R[(j + 1) & 7];
    }

    // ---- head: out[e] = sigmoid(sum_u w3[u]*h_u + b3), quad reduction ----
    float p = W3v * h;
    p += qmov<0xB1>(p);   // quad_perm [1,0,3,2]
    p += qmov<0x4E>(p);   // quad_perm [2,3,0,1]
    if (u == 0) out[ewave + e] = fast_sigmoid(p + B3v);
}

extern "C" void kernel_launch(void* const* d_in, const int* in_sizes, int n_in,
                              void* d_out, int out_size, void* d_ws, size_t ws_size,
                              hipStream_t stream) {
    (void)in_sizes; (void)n_in; (void)d_ws; (void)ws_size; (void)out_size;
    const float* x   = (const float*)d_in[0];
    const float* w1  = (const float*)d_in[1];
    const float* b1  = (const float*)d_in[2];
    const float* w2  = (const float*)d_in[3];
    const float* b2  = (const float*)d_in[4];
    const float* wih = (const float*)d_in[5];
    const float* whh = (const float*)d_in[6];
    const float* bih = (const float*)d_in[7];
    const float* bhh = (const float*)d_in[8];
    const float* w3  = (const float*)d_in[9];
    const float* b3  = (const float*)d_in[10];
    float* out = (float*)d_out;

    // 512 blocks x 256 threads = 2048 waves; 4 lanes per batch element.
    lstm_fused<<<dim3(512), dim3(256), 0, stream>>>(
        x, w1, b1, w2, b2, wih, whh, bih, bhh, w3, b3, out);
}

// Round 3
// 36.170 us; speedup vs baseline: 1.7868x; 1.7868x over previous
//
#include <hip/hip_runtime.h>

// Problem constants (from reference): x[64][32768][15] f32, hidden sizes 4/4/4.
#define SEQ   64
#define BATCH 32768
#define FEAT  15
#define SLAB  (BATCH * FEAT)   // dwords per timestep slab of x

__device__ __forceinline__ float fast_rcp(float x) { return __builtin_amdgcn_rcpf(x); }

__device__ __forceinline__ float fast_sigmoid(float x) {
    // 1 / (1 + e^-x); stable at both extremes (rcp(inf)=0).
    return fast_rcp(1.0f + __expf(-x));
}
__device__ __forceinline__ float fast_tanh(float x) {
    // 1 - 2/(1 + e^{2x}); stable at both extremes.
    return 1.0f - 2.0f * fast_rcp(1.0f + __expf(2.0f * x));
}

// Quad (4-lane) DPP move: CTRL = j*0x55 broadcasts lane j of each quad.
template <int CTRL>
__device__ __forceinline__ float qmov(float v) {
    return __int_as_float(
        __builtin_amdgcn_mov_dpp(__float_as_int(v), CTRL, 0xf, 0xf, false));
}

// 16B-wide load with only 4B alignment guarantee (row stride is 60B).
// aligned(4) keeps codegen correct whether the backend emits dwordx4 or 4x dword.
struct __attribute__((aligned(4))) F4 { float a, b, c, d; };
__device__ __forceinline__ F4 ldf4(const float* p) { return *(const F4*)p; }

__global__ __launch_bounds__(256, 2) void lstm_fused(
    const float* __restrict__ x,
    const float* __restrict__ w1,  const float* __restrict__ b1,
    const float* __restrict__ w2,  const float* __restrict__ b2,
    const float* __restrict__ wih, const float* __restrict__ whh,
    const float* __restrict__ bih, const float* __restrict__ bhh,
    const float* __restrict__ w3,  const float* __restrict__ b3,
    float* __restrict__ out)
{
    const int tid = threadIdx.x;
    const int w   = tid >> 6;          // wave in block
    const int l   = tid & 63;          // lane
    const int u   = l & 3;             // hidden-unit index this lane owns
    const int e   = l >> 2;            // element within the wave's 16
    const int ewave = blockIdx.x * 64 + w * 16;
    const int elem  = ewave + e;       // this quad's batch element

    // lane u loads floats [qoff, qoff+4) of the element's 15-float row.
    // {0,4,8,11}: covers 0..14 with one overlapping dword, never OOB.
    const int qoff = (u == 3) ? 11 : 4 * u;
    const float* xp = x + (size_t)elem * FEAT + qoff;

    // ---- per-lane weights (lane handles hidden unit u of every layer) ----
    float W1[FEAT], W2[4], WI[16], WH[16], BI[4];
#pragma unroll
    for (int f = 0; f < FEAT; ++f) W1[f] = w1[u * FEAT + f];
    const float B1v = b1[u];
#pragma unroll
    for (int j = 0; j < 4; ++j) W2[j] = w2[u * 4 + j];
    const float B2v = b2[u];
#pragma unroll
    for (int g = 0; g < 4; ++g) {
#pragma unroll
        for (int j = 0; j < 4; ++j) {
            WI[g * 4 + j] = wih[(g * 4 + u) * 4 + j];   // torch gate order i,f,g,o
            WH[g * 4 + j] = whh[(g * 4 + u) * 4 + j];
        }
        BI[g] = bih[g * 4 + u] + bhh[g * 4 + u];
    }
    const float W3v = w3[u];
    const float B3v = b3[0];

    float h = 0.0f, c = 0.0f;

    // One LSTM step from this step's quad fragment q (consumed via DPP first,
    // so its registers are dead before the next prefetch lands in them).
    auto step = [&](F4 q) {
        float xv[FEAT];
        xv[0]  = qmov<0x00>(q.a); xv[1]  = qmov<0x00>(q.b);
        xv[2]  = qmov<0x00>(q.c); xv[3]  = qmov<0x00>(q.d);
        xv[4]  = qmov<0x55>(q.a); xv[5]  = qmov<0x55>(q.b);
        xv[6]  = qmov<0x55>(q.c); xv[7]  = qmov<0x55>(q.d);
        xv[8]  = qmov<0xAA>(q.a); xv[9]  = qmov<0xAA>(q.b);
        xv[10] = qmov<0xAA>(q.c); xv[11] = qmov<0xAA>(q.d);
        xv[12] = qmov<0xFF>(q.b); xv[13] = qmov<0xFF>(q.c);
        xv[14] = qmov<0xFF>(q.d);
        // fc1 (unit u), 3-way split accumulation to shorten the dependent chain
        float a0 = B1v, a1 = 0.0f, a2 = 0.0f;
#pragma unroll
        for (int f = 0; f < 5; ++f) a0 = fmaf(W1[f],      xv[f],      a0);
#pragma unroll
        for (int f = 0; f < 5; ++f) a1 = fmaf(W1[5 + f],  xv[5 + f],  a1);
#pragma unroll
        for (int f = 0; f < 5; ++f) a2 = fmaf(W1[10 + f], xv[10 + f], a2);
        const float h1 = fmaxf(a0 + (a1 + a2), 0.0f);
        // fc2 (needs all 4 h1) + sigmoid
        float q0 = qmov<0x00>(h1), q1 = qmov<0x55>(h1), q2 = qmov<0xAA>(h1), q3 = qmov<0xFF>(h1);
        const float a2f = B2v + W2[0] * q0 + W2[1] * q1 + W2[2] * q2 + W2[3] * q3;
        const float h2 = fast_sigmoid(a2f);
        // input-to-gate projection (needs all 4 h2)
        q0 = qmov<0x00>(h2); q1 = qmov<0x55>(h2); q2 = qmov<0xAA>(h2); q3 = qmov<0xFF>(h2);
        float gi = BI[0] + WI[0]  * q0 + WI[1]  * q1 + WI[2]  * q2 + WI[3]  * q3;
        float gf = BI[1] + WI[4]  * q0 + WI[5]  * q1 + WI[6]  * q2 + WI[7]  * q3;
        float gg = BI[2] + WI[8]  * q0 + WI[9]  * q1 + WI[10] * q2 + WI[11] * q3;
        float go = BI[3] + WI[12] * q0 + WI[13] * q1 + WI[14] * q2 + WI[15] * q3;
        // recurrent projection (needs all 4 h_prev)
        q0 = qmov<0x00>(h); q1 = qmov<0x55>(h); q2 = qmov<0xAA>(h); q3 = qmov<0xFF>(h);
        gi += WH[0]  * q0 + WH[1]  * q1 + WH[2]  * q2 + WH[3]  * q3;
        gf += WH[4]  * q0 + WH[5]  * q1 + WH[6]  * q2 + WH[7]  * q3;
        gg += WH[8]  * q0 + WH[9]  * q1 + WH[10] * q2 + WH[11] * q3;
        go += WH[12] * q0 + WH[13] * q1 + WH[14] * q2 + WH[15] * q3;
        const float ig = fast_sigmoid(gi);
        const float fg = fast_sigmoid(gf);
        const float gt = fast_tanh(gg);
        const float og = fast_sigmoid(go);
        c = fmaf(fg, c, ig * gt);
        h = og * fast_tanh(c);
    };

    // ---- depth-8 register prefetch pipeline, statically indexed ----
    F4 Q[8];
#pragma unroll
    for (int j = 0; j < 8; ++j) Q[j] = ldf4(xp + (size_t)j * SLAB);

#pragma unroll 1
    for (int i = 0; i < 7; ++i) {
        const float* xs = xp + (size_t)(8 * i + 8) * SLAB;
#pragma unroll
        for (int j = 0; j < 8; ++j) {
            F4 qcur = Q[j];
            Q[j] = ldf4(xs + (size_t)j * SLAB);  // issue slab s+8 before computing step s
            step(qcur);
        }
    }
#pragma unroll
    for (int j = 0; j < 8; ++j) step(Q[j]);       // steps 56..63, no more prefetch

    // ---- head: out[e] = sigmoid(sum_u w3[u]*h_u + b3), quad reduction ----
    float p = W3v * h;
    p += qmov<0xB1>(p);   // quad_perm [1,0,3,2]
    p += qmov<0x4E>(p);   // quad_perm [2,3,0,1]
    if (u == 0) out[elem] = fast_sigmoid(p + B3v);
}

extern "C" void kernel_launch(void* const* d_in, const int* in_sizes, int n_in,
                              void* d_out, int out_size, void* d_ws, size_t ws_size,
                              hipStream_t stream) {
    (void)in_sizes; (void)n_in; (void)d_ws; (void)ws_size; (void)out_size;
    const float* x   = (const float*)d_in[0];
    const float* w1  = (const float*)d_in[1];
    const float* b1  = (const float*)d_in[2];
    const float* w2  = (const float*)d_in[3];
    const float* b2  = (const float*)d_in[4];
    const float* wih = (const float*)d_in[5];
    const float* whh = (const float*)d_in[6];
    const float* bih = (const float*)d_in[7];
    const float* bhh = (const float*)d_in[8];
    const float* w3  = (const float*)d_in[9];
    const float* b3  = (const float*)d_in[10];
    float* out = (float*)d_out;

    // 512 blocks x 256 threads = 2048 waves; one quad (4 lanes) per batch element.
    lstm_fused<<<dim3(512), dim3(256), 0, stream>>>(
        x, w1, b1, w2, b2, wih, whh, bih, bhh, w3, b3, out);
}

// Round 4
// 35.457 us; speedup vs baseline: 1.8227x; 1.0201x over previous
//
#include <hip/hip_runtime.h>

// Problem constants (from reference): x[64][32768][15] f32, hidden sizes 4/4/4.
#define SEQ   64
#define BATCH 32768
#define FEAT  15
#define SLAB  (BATCH * FEAT)   // dwords per timestep slab of x

#define LOG2E 1.4426950408889634f

__device__ __forceinline__ float fast_rcp(float x)  { return __builtin_amdgcn_rcpf(x); }
__device__ __forceinline__ float ex2(float x)       { return __builtin_amdgcn_exp2f(x); }

// Quad (4-lane) DPP move: CTRL = j*0x55 broadcasts lane j of each quad.
template <int CTRL>
__device__ __forceinline__ float qmov(float v) {
    return __int_as_float(
        __builtin_amdgcn_mov_dpp(__float_as_int(v), CTRL, 0xf, 0xf, false));
}

// 16B-wide load with only 4B alignment guarantee (row stride is 60B).
struct __attribute__((aligned(4))) F4 { float a, b, c, d; };
__device__ __forceinline__ F4 ldf4(const float* p) { return *(const F4*)p; }

__global__ __launch_bounds__(256, 2) void lstm_fused(
    const float* __restrict__ x,
    const float* __restrict__ w1,  const float* __restrict__ b1,
    const float* __restrict__ w2,  const float* __restrict__ b2,
    const float* __restrict__ wih, const float* __restrict__ whh,
    const float* __restrict__ bih, const float* __restrict__ bhh,
    const float* __restrict__ w3,  const float* __restrict__ b3,
    float* __restrict__ out)
{
    const int tid = threadIdx.x;
    const int w   = tid >> 6;          // wave in block
    const int l   = tid & 63;          // lane
    const int u   = l & 3;             // hidden-unit index this lane owns
    const int e   = l >> 2;            // element within the wave's 16
    const int elem = blockIdx.x * 64 + w * 16 + e;   // this quad's batch element

    // lane u loads floats [qoff, qoff+4) of the element's 15-float row.
    // {0,4,8,11}: covers 0..14 with one overlapping dword, never OOB.
    const int qoff = (u == 3) ? 11 : 4 * u;
    const float* xp = x + (size_t)elem * FEAT + qoff;

    // ---- per-lane weights; sigmoid/tanh inputs pre-scaled by +-log2e ----
    // gate order (torch): i, f, g, o.  i,f,o feed sigmoid (scale -log2e),
    // g feeds tanh (scale +2*log2e):  sig(x)=rcp(1+exp2(-L*x)),
    // tanh(x)=1-2*rcp(1+exp2(2L*x)).
    float W1[FEAT], W2[4], WI[16], WH[16], BI[4];
#pragma unroll
    for (int f = 0; f < FEAT; ++f) W1[f] = w1[u * FEAT + f];
    const float B1v = b1[u];
#pragma unroll
    for (int j = 0; j < 4; ++j) W2[j] = -LOG2E * w2[u * 4 + j];
    const float B2v = -LOG2E * b2[u];
#pragma unroll
    for (int g = 0; g < 4; ++g) {
        const float sg = (g == 2) ? (2.0f * LOG2E) : -LOG2E;
#pragma unroll
        for (int j = 0; j < 4; ++j) {
            WI[g * 4 + j] = sg * wih[(g * 4 + u) * 4 + j];
            WH[g * 4 + j] = sg * whh[(g * 4 + u) * 4 + j];
        }
        BI[g] = sg * (bih[g * 4 + u] + bhh[g * 4 + u]);
    }
    const float W3v = -LOG2E * w3[u];
    const float B3v = -LOG2E * b3[0];

    float h = 0.0f, c = 0.0f;

    auto step = [&](F4 q) {
        float xv[FEAT];
        xv[0]  = qmov<0x00>(q.a); xv[1]  = qmov<0x00>(q.b);
        xv[2]  = qmov<0x00>(q.c); xv[3]  = qmov<0x00>(q.d);
        xv[4]  = qmov<0x55>(q.a); xv[5]  = qmov<0x55>(q.b);
        xv[6]  = qmov<0x55>(q.c); xv[7]  = qmov<0x55>(q.d);
        xv[8]  = qmov<0xAA>(q.a); xv[9]  = qmov<0xAA>(q.b);
        xv[10] = qmov<0xAA>(q.c); xv[11] = qmov<0xAA>(q.d);
        xv[12] = qmov<0xFF>(q.b); xv[13] = qmov<0xFF>(q.c);
        xv[14] = qmov<0xFF>(q.d);
        // fc1 (unit u), 3-way split accumulation + relu
        float a0 = B1v, a1 = 0.0f, a2 = 0.0f;
#pragma unroll
        for (int f = 0; f < 5; ++f) a0 = fmaf(W1[f],      xv[f],      a0);
#pragma unroll
        for (int f = 0; f < 5; ++f) a1 = fmaf(W1[5 + f],  xv[5 + f],  a1);
#pragma unroll
        for (int f = 0; f < 5; ++f) a2 = fmaf(W1[10 + f], xv[10 + f], a2);
        const float h1 = fmaxf(a0 + (a1 + a2), 0.0f);
        // fc2 + sigmoid (weights pre-negated/scaled)
        float q0 = qmov<0x00>(h1), q1 = qmov<0x55>(h1), q2 = qmov<0xAA>(h1), q3 = qmov<0xFF>(h1);
        const float a2n = fmaf(W2[0], q0, fmaf(W2[1], q1, fmaf(W2[2], q2, fmaf(W2[3], q3, B2v))));
        const float h2 = fast_rcp(1.0f + ex2(a2n));
        // input-to-gate projection (scaled)
        q0 = qmov<0x00>(h2); q1 = qmov<0x55>(h2); q2 = qmov<0xAA>(h2); q3 = qmov<0xFF>(h2);
        float gi = fmaf(WI[0],  q0, fmaf(WI[1],  q1, fmaf(WI[2],  q2, fmaf(WI[3],  q3, BI[0]))));
        float gf = fmaf(WI[4],  q0, fmaf(WI[5],  q1, fmaf(WI[6],  q2, fmaf(WI[7],  q3, BI[1]))));
        float gg = fmaf(WI[8],  q0, fmaf(WI[9],  q1, fmaf(WI[10], q2, fmaf(WI[11], q3, BI[2]))));
        float go = fmaf(WI[12], q0, fmaf(WI[13], q1, fmaf(WI[14], q2, fmaf(WI[15], q3, BI[3]))));
        // recurrent projection (scaled)
        q0 = qmov<0x00>(h); q1 = qmov<0x55>(h); q2 = qmov<0xAA>(h); q3 = qmov<0xFF>(h);
        gi = fmaf(WH[0],  q0, fmaf(WH[1],  q1, fmaf(WH[2],  q2, fmaf(WH[3],  q3, gi))));
        gf = fmaf(WH[4],  q0, fmaf(WH[5],  q1, fmaf(WH[6],  q2, fmaf(WH[7],  q3, gf))));
        gg = fmaf(WH[8],  q0, fmaf(WH[9],  q1, fmaf(WH[10], q2, fmaf(WH[11], q3, gg))));
        go = fmaf(WH[12], q0, fmaf(WH[13], q1, fmaf(WH[14], q2, fmaf(WH[15], q3, go))));
        const float ig = fast_rcp(1.0f + ex2(gi));
        const float fg = fast_rcp(1.0f + ex2(gf));
        const float og = fast_rcp(1.0f + ex2(go));
        const float gt = fmaf(-2.0f, fast_rcp(1.0f + ex2(gg)), 1.0f);
        c = fmaf(fg, c, ig * gt);
        const float tc = fmaf(-2.0f, fast_rcp(1.0f + ex2(c * (2.0f * LOG2E))), 1.0f);
        h = og * tc;
    };

    F4 Qa[8], Qb[8];
    auto prefetch8 = [&](F4* Q, const float* base) {
#pragma unroll
        for (int j = 0; j < 8; ++j) Q[j] = ldf4(base + (size_t)j * SLAB);
    };
    auto compute8 = [&](F4* Q) {
#pragma unroll
        for (int j = 0; j < 8; ++j) step(Q[j]);
    };

    // ---- software pipeline: 8-step halves, loads pinned above compute ----
    prefetch8(Qa, xp);                                   // slabs 0..7
#pragma unroll 1
    for (int i = 0; i < 3; ++i) {
        const float* bft = xp + (size_t)(16 * i + 8) * SLAB;
        prefetch8(Qb, bft);                              // slabs 8i*2+8..+15
        __builtin_amdgcn_sched_barrier(0);               // loads may not sink
        compute8(Qa);                                    // steps 16i..16i+7
        prefetch8(Qa, bft + (size_t)8 * SLAB);
        __builtin_amdgcn_sched_barrier(0);
        compute8(Qb);                                    // steps 16i+8..16i+15
    }
    prefetch8(Qb, xp + (size_t)56 * SLAB);               // slabs 56..63
    __builtin_amdgcn_sched_barrier(0);
    compute8(Qa);                                        // steps 48..55
    compute8(Qb);                                        // steps 56..63

    // ---- head: out[e] = sigmoid(w3·h + b3), quad reduction (scaled) ----
    float p = W3v * h;
    p += qmov<0xB1>(p);   // quad_perm [1,0,3,2]
    p += qmov<0x4E>(p);   // quad_perm [2,3,0,1]
    if (u == 0) out[elem] = fast_rcp(1.0f + ex2(p + B3v));
}

extern "C" void kernel_launch(void* const* d_in, const int* in_sizes, int n_in,
                              void* d_out, int out_size, void* d_ws, size_t ws_size,
                              hipStream_t stream) {
    (void)in_sizes; (void)n_in; (void)d_ws; (void)ws_size; (void)out_size;
    const float* x   = (const float*)d_in[0];
    const float* w1  = (const float*)d_in[1];
    const float* b1  = (const float*)d_in[2];
    const float* w2  = (const float*)d_in[3];
    const float* b2  = (const float*)d_in[4];
    const float* wih = (const float*)d_in[5];
    const float* whh = (const float*)d_in[6];
    const float* bih = (const float*)d_in[7];
    const float* bhh = (const float*)d_in[8];
    const float* w3  = (const float*)d_in[9];
    const float* b3  = (const float*)d_in[10];
    float* out = (float*)d_out;

    // 512 blocks x 256 threads = 2048 waves; one quad (4 lanes) per batch element.
    lstm_fused<<<dim3(512), dim3(256), 0, stream>>>(
        x, w1, b1, w2, b2, wih, whh, bih, bhh, w3, b3, out);
}

// Round 5
// 33.496 us; speedup vs baseline: 1.9293x; 1.0585x over previous
//
#include <hip/hip_runtime.h>

// Problem constants (from reference): x[64][32768][15] f32, hidden sizes 4/4/4.
#define SEQ   64
#define BATCH 32768
#define FEAT  15
#define SLAB  (BATCH * FEAT)   // dwords per timestep slab of x

#define LOG2E 1.4426950408889634f

typedef float v2f __attribute__((ext_vector_type(2)));

__device__ __forceinline__ float fast_rcp(float x) { return __builtin_amdgcn_rcpf(x); }
__device__ __forceinline__ float ex2(float x)      { return __builtin_amdgcn_exp2f(x); }
// sig2(t) = 1/(1+2^t).  sigmoid(x) = sig2(-L*x); tanh(x) = 1 - 2*sig2(2L*x).
__device__ __forceinline__ float sig2(float t)     { return fast_rcp(1.0f + ex2(t)); }

// Quad (4-lane) DPP move: CTRL = j*0x55 broadcasts lane j of each quad;
// 0xB1 = quad_perm [1,0,3,2] (xor1), 0x4E = [2,3,0,1] (xor2).
template <int CTRL>
__device__ __forceinline__ float qmov(float v) {
    return __int_as_float(
        __builtin_amdgcn_mov_dpp(__float_as_int(v), CTRL, 0xf, 0xf, false));
}

// packed f32 fma: a*b + c with -ffp-contract=fast -> v_pk_fma_f32 on gfx950
__device__ __forceinline__ v2f fma2(v2f a, v2f b, v2f c) { return a * b + c; }

struct Fq { float a, b, c, d; };   // one step's 4 own-features (static regs)

__global__ __launch_bounds__(256, 2) void lstm_fused(
    const float* __restrict__ x,
    const float* __restrict__ w1,  const float* __restrict__ b1,
    const float* __restrict__ w2,  const float* __restrict__ b2,
    const float* __restrict__ wih, const float* __restrict__ whh,
    const float* __restrict__ bih, const float* __restrict__ bhh,
    const float* __restrict__ w3,  const float* __restrict__ b3,
    float* __restrict__ out)
{
    const int tid = threadIdx.x;
    const int w   = tid >> 6;          // wave in block
    const int l   = tid & 63;          // lane
    const int u   = l & 3;             // lane-in-quad
    const int e   = l >> 2;            // element within the wave's 16
    const int elem = blockIdx.x * 64 + w * 16 + e;   // this quad's batch element

    // lane u owns features [qoff, qoff+4): {0,4,8,11}; feature 11 is loaded by
    // both lane2 (k=3) and lane3 (k=0) - lane3's copy is weight-zeroed.
    const int qoff = (u == 3) ? 11 : 4 * u;
    const float* xp = x + (size_t)elem * FEAT + qoff;

    // ---- weights ----
    // fc1: per-lane partial dot for ALL 4 units over own 4 features.
    v2f W1a[4], W1b[4], SE[4];
#pragma unroll
    for (int j = 0; j < 4; ++j) {
        const float* r = w1 + j * FEAT + qoff;
        W1a[j] = v2f{(u == 3) ? 0.0f : r[0], r[1]};   // dedup feature 11
        W1b[j] = v2f{r[2], r[3]};
        SE[j]  = v2f{(u == 0) ? b1[j] : 0.0f, 0.0f};  // bias seeded on lane0 only
    }
    // fc2 (unit u), pre-scaled by -log2e for sig2
    float W2s[4];
#pragma unroll
    for (int j = 0; j < 4; ++j) W2s[j] = -LOG2E * w2[u * 4 + j];
    const float B2v = -LOG2E * b2[u];
    // gates (torch order i,f,g,o): lane u owns all 4 gates of unit u.
    // i,f,o scaled -log2e (sigmoid); g scaled +2log2e (tanh).
    v2f WIp[4][2], WHp[4][2], BIg[4];
#pragma unroll
    for (int g = 0; g < 4; ++g) {
        const float sg = (g == 2) ? (2.0f * LOG2E) : -LOG2E;
        const int row = (g * 4 + u) * 4;
        WIp[g][0] = v2f{sg * wih[row + 0], sg * wih[row + 1]};
        WIp[g][1] = v2f{sg * wih[row + 2], sg * wih[row + 3]};
        WHp[g][0] = v2f{sg * whh[row + 0], sg * whh[row + 1]};
        WHp[g][1] = v2f{sg * whh[row + 2], sg * whh[row + 3]};
        BIg[g]    = v2f{sg * (bih[g * 4 + u] + bhh[g * 4 + u]), 0.0f};
    }
    const float W3v = -LOG2E * w3[u];
    const float B3v = -LOG2E * b3[0];

    float h = 0.0f, c = 0.0f;

    auto step = [&](Fq q) {
        // fc1: own-feature partials for all 4 units (packed), then hadd
        const v2f f01 = v2f{q.a, q.b}, f23 = v2f{q.c, q.d};
        float P[4];
#pragma unroll
        for (int j = 0; j < 4; ++j) {
            const v2f p2 = fma2(W1a[j], f01, fma2(W1b[j], f23, SE[j]));
            P[j] = p2.x + p2.y;
        }
        // quad butterfly all-reduce: every lane gets all 4 full fc1 dots
#pragma unroll
        for (int j = 0; j < 4; ++j) {
            P[j] += qmov<0xB1>(P[j]);
            P[j] += qmov<0x4E>(P[j]);
            P[j] = fmaxf(P[j], 0.0f);          // relu
        }
        // fc2 (unit u) + sigmoid
        const float a2n = fmaf(W2s[0], P[0], fmaf(W2s[1], P[1],
                          fmaf(W2s[2], P[2], fmaf(W2s[3], P[3], B2v))));
        const float h2 = sig2(a2n);
        // broadcast h2 across the quad as two packed pairs
        const v2f q01 = v2f{qmov<0x00>(h2), qmov<0x55>(h2)};
        const v2f q23 = v2f{qmov<0xAA>(h2), qmov<0xFF>(h2)};
        // input-to-gate projection (packed over the j index)
        v2f A[4];
#pragma unroll
        for (int g = 0; g < 4; ++g)
            A[g] = fma2(WIp[g][0], q01, fma2(WIp[g][1], q23, BIg[g]));
        // recurrent projection
        const v2f h01 = v2f{qmov<0x00>(h), qmov<0x55>(h)};
        const v2f h23 = v2f{qmov<0xAA>(h), qmov<0xFF>(h)};
#pragma unroll
        for (int g = 0; g < 4; ++g)
            A[g] = fma2(WHp[g][0], h01, fma2(WHp[g][1], h23, A[g]));
        // activations (inputs pre-scaled)
        const float ig = sig2(A[0].x + A[0].y);
        const float fg = sig2(A[1].x + A[1].y);
        const float gt = fmaf(-2.0f, sig2(A[2].x + A[2].y), 1.0f);
        const float og = sig2(A[3].x + A[3].y);
        c = fmaf(fg, c, ig * gt);
        const float tc = fmaf(-2.0f, sig2(c * (2.0f * LOG2E)), 1.0f);
        h = og * tc;
    };

    Fq Qa[8], Qb[8];
    auto ld4 = [](const float* p) {
        Fq r; r.a = p[0]; r.b = p[1]; r.c = p[2]; r.d = p[3]; return r;
    };
    auto prefetch8 = [&](Fq* Q, const float* base) {
#pragma unroll
        for (int j = 0; j < 8; ++j) Q[j] = ld4(base + (size_t)j * SLAB);
    };
    auto compute8 = [&](Fq* Q) {
#pragma unroll
        for (int j = 0; j < 8; ++j) step(Q[j]);
    };

    // ---- software pipeline: 8-step halves, loads pinned above compute ----
    prefetch8(Qa, xp);                                   // slabs 0..7
#pragma unroll 1
    for (int i = 0; i < 3; ++i) {
        const float* bft = xp + (size_t)(16 * i + 8) * SLAB;
        prefetch8(Qb, bft);
        __builtin_amdgcn_sched_barrier(0);               // loads may not sink
        compute8(Qa);                                    // steps 16i..16i+7
        prefetch8(Qa, bft + (size_t)8 * SLAB);
        __builtin_amdgcn_sched_barrier(0);
        compute8(Qb);                                    // steps 16i+8..16i+15
    }
    prefetch8(Qb, xp + (size_t)56 * SLAB);               // slabs 56..63
    __builtin_amdgcn_sched_barrier(0);
    compute8(Qa);                                        // steps 48..55
    compute8(Qb);                                        // steps 56..63

    // ---- head: out[e] = sigmoid(w3·h + b3), quad reduction (scaled) ----
    float p = W3v * h;
    p += qmov<0xB1>(p);
    p += qmov<0x4E>(p);
    if (u == 0) out[elem] = sig2(p + B3v);
}

extern "C" void kernel_launch(void* const* d_in, const int* in_sizes, int n_in,
                              void* d_out, int out_size, void* d_ws, size_t ws_size,
                              hipStream_t stream) {
    (void)in_sizes; (void)n_in; (void)d_ws; (void)ws_size; (void)out_size;
    const float* x   = (const float*)d_in[0];
    const float* w1  = (const float*)d_in[1];
    const float* b1  = (const float*)d_in[2];
    const float* w2  = (const float*)d_in[3];
    const float* b2  = (const float*)d_in[4];
    const float* wih = (const float*)d_in[5];
    const float* whh = (const float*)d_in[6];
    const float* bih = (const float*)d_in[7];
    const float* bhh = (const float*)d_in[8];
    const float* w3  = (const float*)d_in[9];
    const float* b3  = (const float*)d_in[10];
    float* out = (float*)d_out;

    // 512 blocks x 256 threads = 2048 waves; one quad (4 lanes) per batch element.
    lstm_fused<<<dim3(512), dim3(256), 0, stream>>>(
        x, w1, b1, w2, b2, wih, whh, bih, bhh, w3, b3, out);
}